// Round 1
// baseline (203.862 us; speedup 1.0000x reference)
//
#include <hip/hip_runtime.h>
#include <math.h>

#define BB 4
#define SQL 512
#define SKL 512
#define HH 256
#define AA 128

// ---------------------------------------------------------------------------
// Kernel 1: Qt_s = 2*(Q@W_q), Kt_s = 2*(K@W_k)   (pre-scaled by 2 for tanh)
// grid 512 x 128 threads. blocks [0,256): Q rows; [256,512): K rows.
// Each block computes 8 output rows; thread = output column a (0..127).
// ---------------------------------------------------------------------------
__global__ __launch_bounds__(128) void proj_kernel(
    const float* __restrict__ Q, const float* __restrict__ K,
    const float* __restrict__ Wq, const float* __restrict__ Wk,
    float* __restrict__ Qt, float* __restrict__ Kt)
{
    __shared__ float rows[8][HH];   // 8 KB
    int bid = blockIdx.x;
    int tid = threadIdx.x;
    const float* X; const float* W; float* Y; int r0;
    if (bid < 256) { X = Q; W = Wq; Y = Qt; r0 = bid * 8; }
    else           { X = K; W = Wk; Y = Kt; r0 = (bid - 256) * 8; }

    // stage 8 contiguous input rows (2048 floats, coalesced)
    for (int i = tid; i < 8 * HH; i += 128)
        rows[i >> 8][i & 255] = X[(size_t)r0 * HH + i];
    __syncthreads();

    float acc[8] = {0.f,0.f,0.f,0.f,0.f,0.f,0.f,0.f};
    for (int h = 0; h < HH; ++h) {
        float w = W[h * AA + tid];          // coalesced, L2-hot
        #pragma unroll
        for (int r = 0; r < 8; ++r) acc[r] = fmaf(rows[r][h], w, acc[r]);
    }
    #pragma unroll
    for (int r = 0; r < 8; ++r)
        Y[(size_t)(r0 + r) * AA + tid] = 2.0f * acc[r];
}

// ---------------------------------------------------------------------------
// Kernel 2: fused scores + softmax -> weights.
// grid = B*SQ/4 = 512 blocks, 256 threads. Block handles 4 q-rows of one batch.
//   score[q][k] = sum_a tanh( (Qt2[q][a] + Kt2[k][a]) / 2 ) * v[a]
//              = S_all - sum_a 2*v[a] * rcp(exp(Qt2+Kt2) + 1)
// Kt staged in LDS 64-k chunks, stride 129 (pad +1) -> conflict-free.
// Thread = (k_local = tid&63, a_group = tid>>6 covering 32 a's), reuses the
// staged Kt element across the 4 q-rows.
// ---------------------------------------------------------------------------
__global__ __launch_bounds__(256) void score_kernel(
    const float* __restrict__ Qt, const float* __restrict__ Kt,
    const float* __restrict__ v, float* __restrict__ weights)
{
    __shared__ float kt_lds[64 * 129];   // 33 KB
    __shared__ float qrow[4][AA];        // 2 KB
    __shared__ float vv[AA];             // 0.5 KB
    __shared__ float score[4][SKL];      // 8 KB
    __shared__ float part[16][64];       // 4 KB  [qi*4+ag][k_local]

    int tid = threadIdx.x;
    int b  = blockIdx.x >> 7;            // 128 blocks per batch
    int q0 = (blockIdx.x & 127) << 2;

    for (int i = tid; i < 4 * AA; i += 256)
        qrow[i >> 7][i & 127] = Qt[(size_t)(b * SQL + q0) * AA + i];
    if (tid < AA) vv[tid] = v[tid];
    __syncthreads();

    int k_local = tid & 63;
    int ag      = tid >> 6;              // a in [ag*32, ag*32+32)

    // S_all = sum_a v[a]
    float S_all = 0.f;
    #pragma unroll
    for (int j = 0; j < AA; ++j) S_all += vv[j];

    for (int c = 0; c < 8; ++c) {
        int k0 = c * 64;
        // stage 64 Kt rows (8192 floats, coalesced reads)
        for (int i = tid; i < 64 * AA; i += 256) {
            int r = i >> 7, col = i & 127;
            kt_lds[r * 129 + col] = Kt[(size_t)(b * SKL + k0 + r) * AA + col];
        }
        __syncthreads();

        float p[4] = {0.f,0.f,0.f,0.f};
        int base = k_local * 129 + ag * 32;
        #pragma unroll
        for (int j = 0; j < 32; ++j) {
            int a = ag * 32 + j;
            float kv = kt_lds[base + j];       // 2*Kt, bank-conflict-free
            float va = vv[a];                  // broadcast
            float v2 = va + va;                // 2*v[a]
            #pragma unroll
            for (int qi = 0; qi < 4; ++qi) {
                float x2 = qrow[qi][a] + kv;   // = 2*(Qt+Kt)
                x2 = fminf(60.f, fmaxf(-60.f, x2));
                float t = __expf(x2);
                float r = __builtin_amdgcn_rcpf(t + 1.0f);
                p[qi] = fmaf(v2, r, p[qi]);    // accumulate 2 v[a] / (e^{2x}+1)
            }
        }
        #pragma unroll
        for (int qi = 0; qi < 4; ++qi)
            part[qi * 4 + ag][k_local] = p[qi];
        __syncthreads();

        // reduce the 4 a-groups: 256 threads cover 4q x 64k
        {
            int qi = tid >> 6, kk = tid & 63;
            score[qi][k0 + kk] = S_all -
                (part[qi * 4 + 0][kk] + part[qi * 4 + 1][kk] +
                 part[qi * 4 + 2][kk] + part[qi * 4 + 3][kk]);
        }
        // no sync needed here: next staging writes kt_lds only after each
        // thread passed the post-staging sync; part is rewritten only after it.
    }
    __syncthreads();

    // softmax: wave w handles q-row w (4 waves, 4 rows)
    {
        int qi = tid >> 6, lane = tid & 63;
        float m = -1e30f;
        for (int k = lane; k < SKL; k += 64) m = fmaxf(m, score[qi][k]);
        #pragma unroll
        for (int off = 32; off; off >>= 1) m = fmaxf(m, __shfl_xor(m, off));
        float s = 0.f;
        for (int k = lane; k < SKL; k += 64) {
            float e = __expf(score[qi][k] - m);
            score[qi][k] = e;
            s += e;
        }
        #pragma unroll
        for (int off = 32; off; off >>= 1) s += __shfl_xor(s, off);
        float rinv = 1.0f / s;
        size_t rowoff = (size_t)(b * SQL + q0 + qi) * SKL;
        for (int k = lane; k < SKL; k += 64)
            weights[rowoff + k] = score[qi][k] * rinv;
    }
}

// ---------------------------------------------------------------------------
// Kernel 3: out = (weights @ V) @ W_o + b_o
// grid = B * (SQ/8) = 256 blocks, 256 threads. Block = (b, 8 q-rows).
// Phase A: att[8][256] = weights@V with V staged in 32-k LDS chunks.
// Phase B: out = att@W_o + b_o via LDS round-trip of att.
// ---------------------------------------------------------------------------
__global__ __launch_bounds__(256) void out_kernel(
    const float* __restrict__ weights, const float* __restrict__ V,
    const float* __restrict__ Wo, const float* __restrict__ bo,
    float* __restrict__ out)
{
    __shared__ float v_lds[32][HH];   // 32 KB
    __shared__ float w_lds[8][32];    // 1 KB
    __shared__ float att[8][HH];      // 8 KB

    int tid = threadIdx.x;
    int b  = blockIdx.x >> 6;         // 64 q-tiles per batch
    int q0 = (blockIdx.x & 63) << 3;

    float acc[8] = {0.f,0.f,0.f,0.f,0.f,0.f,0.f,0.f};
    for (int c = 0; c < 16; ++c) {
        int k0 = c * 32;
        {   // stage 8x32 weight tile (one element per thread)
            int qi = tid >> 5, kk = tid & 31;
            w_lds[qi][kk] = weights[(size_t)(b * SQL + q0 + qi) * SKL + k0 + kk];
        }
        // stage 32x256 V tile (coalesced)
        for (int i = tid; i < 32 * HH; i += 256)
            v_lds[i >> 8][i & 255] = V[(size_t)(b * SKL + k0) * HH + i];
        __syncthreads();

        #pragma unroll 4
        for (int k = 0; k < 32; ++k) {
            float vk = v_lds[k][tid];          // consecutive lanes -> no conflict
            #pragma unroll
            for (int qi = 0; qi < 8; ++qi)
                acc[qi] = fmaf(w_lds[qi][k], vk, acc[qi]);
        }
        __syncthreads();
    }

    #pragma unroll
    for (int qi = 0; qi < 8; ++qi) att[qi][tid] = acc[qi];
    __syncthreads();

    float ob = bo[tid];
    float acc2[8];
    #pragma unroll
    for (int qi = 0; qi < 8; ++qi) acc2[qi] = ob;
    for (int h = 0; h < HH; ++h) {
        float w = Wo[h * HH + tid];            // coalesced, L2-hot
        #pragma unroll
        for (int qi = 0; qi < 8; ++qi)
            acc2[qi] = fmaf(att[qi][h], w, acc2[qi]);   // att broadcast
    }
    #pragma unroll
    for (int qi = 0; qi < 8; ++qi)
        out[(size_t)(b * SQL + q0 + qi) * HH + tid] = acc2[qi];
}

// ---------------------------------------------------------------------------
extern "C" void kernel_launch(void* const* d_in, const int* in_sizes, int n_in,
                              void* d_out, int out_size, void* d_ws, size_t ws_size,
                              hipStream_t stream)
{
    const float* Q  = (const float*)d_in[0];
    const float* K  = (const float*)d_in[1];
    const float* V  = (const float*)d_in[2];
    const float* Wq = (const float*)d_in[3];
    const float* Wk = (const float*)d_in[4];
    const float* v  = (const float*)d_in[5];
    const float* Wo = (const float*)d_in[6];
    const float* bo = (const float*)d_in[7];

    float* out     = (float*)d_out;                       // (B,SQ,H) = 524288
    float* weights = out + (size_t)BB * SQL * HH;         // (B,SQ,SK) = 1048576

    float* Qt = (float*)d_ws;                             // (B*SQ, A) = 262144
    float* Kt = Qt + (size_t)BB * SQL * AA;               // (B*SK, A) = 262144

    proj_kernel <<<512, 128, 0, stream>>>(Q, K, Wq, Wk, Qt, Kt);
    score_kernel<<<512, 256, 0, stream>>>(Qt, Kt, v, weights);
    out_kernel  <<<256, 256, 0, stream>>>(weights, V, Wo, bo, out);
}